// Round 9
// baseline (393.390 us; speedup 1.0000x reference)
//
#include <hip/hip_runtime.h>
#include <math.h>
#include <stdint.h>

// Problem constants (fixed by setup_inputs)
#define NTOK 16384      // B*S = 4*4096
#define SEQ  4096
#define HD   2048
#define MD   128
#define NCH  64         // number of chunks == N_SLOTS (ptr never wraps)
#define CHK  64         // chunk_size

typedef __attribute__((ext_vector_type(8))) _Float16 half8;  // 8 fp16 = 4 VGPRs
typedef __attribute__((ext_vector_type(4))) float floatx4;   // MFMA accumulator

__device__ __forceinline__ void gload_lds16(const void* g, void* l) {
    // async global->LDS, 16B per lane; LDS dest = wave-uniform base + lane*16
    __builtin_amdgcn_global_load_lds(
        (const __attribute__((address_space(1))) unsigned int*)(uintptr_t)g,
        (__attribute__((address_space(3))) unsigned int*)(uintptr_t)l,
        16, 0, 0);
}

// ---------------------------------------------------------------------------
// K0: fused weight prep. Blocks 0..4095: convert weights to fp16
//   (Wcath = [Wq;Wk;Wv] 384x2048, Woh 2048x128). Blocks 4096..4223:
//   G = W_out^T @ W_out (f32), one column per block — arithmetic identical
//   to the previous standalone gmat_kernel (same serial j-loop per (a,b)).
// ---------------------------------------------------------------------------
__global__ __launch_bounds__(256) void prep_kernel(
    const float* __restrict__ Wq, const float* __restrict__ Wk,
    const float* __restrict__ Wv, const float* __restrict__ Wo,
    _Float16* __restrict__ Wcath, _Float16* __restrict__ Woh,
    float* __restrict__ G)
{
    if (blockIdx.x < 4096) {
        int i = blockIdx.x * 256 + threadIdx.x;   // 0 .. 1048575
        if (i < 384 * HD) {
            int r = i >> 11;
            float val;
            if (r < 128)      val = Wq[i];
            else if (r < 256) val = Wk[i - 128 * HD];
            else              val = Wv[i - 256 * HD];
            Wcath[i] = (_Float16)val;
        } else {
            int j = i - 384 * HD;                 // 0 .. 262143
            Woh[j] = (_Float16)Wo[j];
        }
    } else {
        __shared__ float col[HD];
        int a = blockIdx.x - 4096;                // 0..127
        int tid = threadIdx.x;
        for (int j = tid; j < HD; j += 256) col[j] = Wo[(size_t)j * MD + a];
        __syncthreads();
        if (tid < 128) {
            int b = tid;
            float s = 0.f;
            for (int j = 0; j < HD; ++j) s = fmaf(col[j], Wo[(size_t)j * MD + b], s);
            G[a * MD + b] = s;
        }
    }
}

// ---------------------------------------------------------------------------
// K1 (verified R7): proj GEMM, grid (256,3), 3 blocks/CU, BK=64, dbuf,
//   one __syncthreads per K-step, async B staging (pre-swizzled source,
//   rule 21), A via regs issue-early/write-late, XOR swizzle ((row&7)<<4),
//   fused k/v l2norm epilogue (y=1/2) + gate/q epilogue (y=0).
// ---------------------------------------------------------------------------
__global__ __launch_bounds__(256, 3) void gemm_proj_mfma(
    const float* __restrict__ x, const _Float16* __restrict__ Wcath,
    const float* __restrict__ Wgw, const float* __restrict__ gb,
    float* __restrict__ q, float* __restrict__ k, float* __restrict__ v,
    float* __restrict__ wg)
{
    __shared__ _Float16 As[2][64 * 64];    // 8 KB per buffer
    __shared__ _Float16 Bs[2][128 * 64];   // 16 KB per buffer
    floatx4 acc[2][4];
    #pragma unroll
    for (int i = 0; i < 2; ++i)
        #pragma unroll
        for (int j = 0; j < 4; ++j) acc[i][j] = (floatx4){0.f, 0.f, 0.f, 0.f};

    const int tid  = threadIdx.x;
    const int wave = tid >> 6, lane = tid & 63;
    const int wm = wave & 1, wn = wave >> 1;   // wave -> 32-row half x 64-col half
    const int row0 = blockIdx.x * 64;
    const int col0 = blockIdx.y * 128;
    const bool do_gate = (blockIdx.y == 0);

    const int ar0 = tid >> 3;                 // rows 0..31 ; second row = ar0+32
    const int ac0 = (tid & 7) ^ (ar0 & 7);    // pre-swizzled 8-f32 column group
    const float* xA0 = x + (size_t)(row0 + ar0) * HD + ac0 * 8;
    const float* xA1 = x + (size_t)(row0 + ar0 + 32) * HD + ac0 * 8;
    const float* wgp = Wgw + ac0 * 8;

    float gacc0 = 0.f, gacc1 = 0.f;
    float4 a00, a01, a10, a11, g0, g1;

#define STAGE_B(buf_, k0_) do {                                               \
        _Pragma("unroll")                                                     \
        for (int rnd = 0; rnd < 4; ++rnd) {                                   \
            int sg = rnd * 4 + wave;                                          \
            int br = sg * 8 + (lane >> 3);                                    \
            int bc = (lane & 7) ^ (br & 7);                                   \
            gload_lds16(Wcath + (size_t)(col0 + br) * HD + (k0_) + bc * 8,    \
                        (char*)Bs[buf_] + sg * 1024);                         \
        } } while (0)

#define LOAD_A(k0_) do {                                                      \
        a00 = *(const float4*)(xA0 + (k0_));                                  \
        a01 = *(const float4*)(xA0 + (k0_) + 4);                              \
        a10 = *(const float4*)(xA1 + (k0_));                                  \
        a11 = *(const float4*)(xA1 + (k0_) + 4);                              \
        if (do_gate) {                                                        \
            g0 = *(const float4*)(wgp + (k0_));                               \
            g1 = *(const float4*)(wgp + (k0_) + 4);                           \
        } } while (0)

#define FINISH_A(buf_) do {                                                   \
        if (do_gate) {                                                        \
            gacc0 += a00.x*g0.x + a00.y*g0.y + a00.z*g0.z + a00.w*g0.w        \
                   + a01.x*g1.x + a01.y*g1.y + a01.z*g1.z + a01.w*g1.w;       \
            gacc1 += a10.x*g0.x + a10.y*g0.y + a10.z*g0.z + a10.w*g0.w        \
                   + a11.x*g1.x + a11.y*g1.y + a11.z*g1.z + a11.w*g1.w;       \
        }                                                                     \
        half8 h0, h1;                                                         \
        h0[0] = (_Float16)a00.x; h0[1] = (_Float16)a00.y;                     \
        h0[2] = (_Float16)a00.z; h0[3] = (_Float16)a00.w;                     \
        h0[4] = (_Float16)a01.x; h0[5] = (_Float16)a01.y;                     \
        h0[6] = (_Float16)a01.z; h0[7] = (_Float16)a01.w;                     \
        h1[0] = (_Float16)a10.x; h1[1] = (_Float16)a10.y;                     \
        h1[2] = (_Float16)a10.z; h1[3] = (_Float16)a10.w;                     \
        h1[4] = (_Float16)a11.x; h1[5] = (_Float16)a11.y;                     \
        h1[6] = (_Float16)a11.z; h1[7] = (_Float16)a11.w;                     \
        *(half8*)((char*)As[buf_] + tid * 16)        = h0;                    \
        *(half8*)((char*)As[buf_] + 4096 + tid * 16) = h1;                    \
    } while (0)

#define COMPUTE(buf_) do {                                                    \
        half8 af[2][2], bf[4][2];                                             \
        _Pragma("unroll")                                                     \
        for (int i = 0; i < 2; ++i) {                                         \
            int r  = wm * 32 + i * 16 + (lane & 15);                          \
            int rb = r * 128 + (lane >> 4) * 16;                              \
            int sw = (r & 7) << 4;                                            \
            af[i][0] = *(const half8*)((const char*)As[buf_] + ( rb       ^ sw)); \
            af[i][1] = *(const half8*)((const char*)As[buf_] + ((rb + 64) ^ sw)); \
        }                                                                     \
        _Pragma("unroll")                                                     \
        for (int j = 0; j < 4; ++j) {                                         \
            int r  = wn * 64 + j * 16 + (lane & 15);                          \
            int rb = r * 128 + (lane >> 4) * 16;                              \
            int sw = (r & 7) << 4;                                            \
            bf[j][0] = *(const half8*)((const char*)Bs[buf_] + ( rb       ^ sw)); \
            bf[j][1] = *(const half8*)((const char*)Bs[buf_] + ((rb + 64) ^ sw)); \
        }                                                                     \
        _Pragma("unroll")                                                     \
        for (int ks = 0; ks < 2; ++ks)                                        \
            _Pragma("unroll")                                                 \
            for (int i = 0; i < 2; ++i)                                       \
                _Pragma("unroll")                                             \
                for (int j = 0; j < 4; ++j)                                   \
                    acc[i][j] = __builtin_amdgcn_mfma_f32_16x16x32_f16(       \
                        af[i][ks], bf[j][ks], acc[i][j], 0, 0, 0);            \
    } while (0)

    STAGE_B(0, 0);
    LOAD_A(0);
    FINISH_A(0);
    __syncthreads();

    int cur = 0;
    for (int t = 0; t < HD / 64; ++t) {
        if (t < HD / 64 - 1) {
            STAGE_B(cur ^ 1, (t + 1) * 64);   // async, drains at the barrier
            LOAD_A((t + 1) * 64);             // regs, consumed after MFMA
        }
        COMPUTE(cur);
        if (t < HD / 64 - 1) FINISH_A(cur ^ 1);
        __syncthreads();
        cur ^= 1;
    }

    if (do_gate) {
        // ---- gate epilogue + plain q store ----
        gacc0 += __shfl_xor(gacc0, 1);
        gacc0 += __shfl_xor(gacc0, 2);
        gacc0 += __shfl_xor(gacc0, 4);
        gacc1 += __shfl_xor(gacc1, 1);
        gacc1 += __shfl_xor(gacc1, 2);
        gacc1 += __shfl_xor(gacc1, 4);
        if ((tid & 7) == 0) {
            wg[row0 + ar0]      = 1.f / (1.f + expf(-(gacc0 + gb[0])));
            wg[row0 + ar0 + 32] = 1.f / (1.f + expf(-(gacc1 + gb[0])));
        }
        #pragma unroll
        for (int i = 0; i < 2; ++i) {
            int m = row0 + wm * 32 + i * 16 + (lane >> 4) * 4;
            #pragma unroll
            for (int j = 0; j < 4; ++j) {
                int c = wn * 64 + j * 16 + (lane & 15);
                #pragma unroll
                for (int r = 0; r < 4; ++r)
                    q[(size_t)(m + r) * MD + c] = acc[i][j][r];
            }
        }
    } else {
        // ---- fused l2norm epilogue for k (y=1) / v (y=2) ----
        float* t_s = (float*)&Bs[0][0];           // [64][128] f32 overlay
        #pragma unroll
        for (int i = 0; i < 2; ++i) {
            int m = wm * 32 + i * 16 + (lane >> 4) * 4;
            #pragma unroll
            for (int j = 0; j < 4; ++j) {
                int c = wn * 64 + j * 16 + (lane & 15);
                #pragma unroll
                for (int r = 0; r < 4; ++r)
                    t_s[(m + r) * 128 + c] = acc[i][j][r];
            }
        }
        __syncthreads();
        float* dst = (blockIdx.y == 1) ? k : v;
        #pragma unroll
        for (int rr = 0; rr < 16; ++rr) {
            int row = wave * 16 + rr;
            float x0 = t_s[row * 128 + 2 * lane];
            float x1 = t_s[row * 128 + 2 * lane + 1];
            float ss = x0 * x0 + x1 * x1;
            #pragma unroll
            for (int off = 32; off > 0; off >>= 1) ss += __shfl_xor(ss, off);
            float inv = 1.f / fmaxf(sqrtf(ss), 1e-12f);
            float2 o; o.x = x0 * inv; o.y = x1 * inv;
            *(float2*)&dst[(size_t)(row0 + row) * MD + 2 * lane] = o;
        }
    }
#undef STAGE_B
#undef LOAD_A
#undef FINISH_A
#undef COMPUTE
}

// ---------------------------------------------------------------------------
// K2a: per-(chunk,batch) partial aggregation. grid 256 = chunk*4 + batch.
// ---------------------------------------------------------------------------
__global__ __launch_bounds__(256) void agg_part_kernel(
    const float* __restrict__ kn, const float* __restrict__ vn,
    const float* __restrict__ w,
    float* __restrict__ kpart, float* __restrict__ vpart,
    float* __restrict__ wpart)
{
    int t = blockIdx.x >> 2, b = blockIdx.x & 3;
    int tid = threadIdx.x;
    int d = tid & 127, h = tid >> 7;
    int base_row = b * SEQ + t * CHK;

    float ka = 0.f, va = 0.f;
    for (int c = h * 32; c < h * 32 + 32; ++c) {
        int row = base_row + c;
        float wv = w[row];
        ka = fmaf(wv, kn[(size_t)row * MD + d], ka);
        va = fmaf(wv, vn[(size_t)row * MD + d], va);
    }
    __shared__ float sk[128], sv[128];
    if (h == 1) { sk[d] = ka; sv[d] = va; }
    __syncthreads();
    if (h == 0) {
        kpart[(size_t)blockIdx.x * 128 + d] = ka + sk[d];
        vpart[(size_t)blockIdx.x * 128 + d] = va + sv[d];
    }
    if (tid < 64) {
        float wv = w[base_row + tid];
        #pragma unroll
        for (int off = 32; off > 0; off >>= 1) wv += __shfl_xor(wv, off);
        if (tid == 0) wpart[blockIdx.x] = wv;
    }
}

// ---------------------------------------------------------------------------
// K2b: combine partials per chunk, normalize, emit kaT / vagg / wstr.
// grid 64, 128 threads (2 waves)
// ---------------------------------------------------------------------------
__global__ __launch_bounds__(128) void agg_combine_kernel(
    const float* __restrict__ kpart, const float* __restrict__ vpart,
    const float* __restrict__ wpart,
    float* __restrict__ kaT, float* __restrict__ vagg, float* __restrict__ wstr)
{
    int t = blockIdx.x;
    int d = threadIdx.x;              // 0..127
    int wave = d >> 6, lane = d & 63;
    float ku = 0.f, vu = 0.f;
    #pragma unroll
    for (int b = 0; b < 4; ++b) {
        ku += kpart[(size_t)(t * 4 + b) * 128 + d];
        vu += vpart[(size_t)(t * 4 + b) * 128 + d];
    }
    float wsum = wpart[t * 4] + wpart[t * 4 + 1] + wpart[t * 4 + 2] + wpart[t * 4 + 3];
    float winv = 1.f / fmaxf(wsum, 1e-8f);
    ku *= winv; vu *= winv;

    __shared__ float red[4];
    float ks = ku * ku, vs = vu * vu;
    #pragma unroll
    for (int off = 32; off > 0; off >>= 1) {
        ks += __shfl_xor(ks, off);
        vs += __shfl_xor(vs, off);
    }
    if (lane == 0) { red[wave] = ks; red[2 + wave] = vs; }
    __syncthreads();
    float kinv = 1.f / fmaxf(sqrtf(red[0] + red[1]), 1e-12f);
    float vinv = 1.f / fmaxf(sqrtf(red[2] + red[3]), 1e-12f);
    kaT[d * NCH + t] = ku * kinv;
    vagg[t * MD + d] = vu * vinv;
    if (d == 0) wstr[t] = wsum * (1.f / 256.f);
}

// ---------------------------------------------------------------------------
// K3 v2: causal slot attention + G-norm scale; writes r (fp16) for out GEMM.
//   256 blocks (1/CU), 512 threads (8 waves), 64 rows/block; kaT+vagg+G
//   staged once into 128 KB LDS. Arithmetic order identical to v1.
// ---------------------------------------------------------------------------
__global__ __launch_bounds__(512, 1) void attn_kernel(
    const float* __restrict__ q, const float* __restrict__ kaT,
    const float* __restrict__ vagg, const float* __restrict__ G,
    const float* __restrict__ logbeta, _Float16* __restrict__ rsh16)
{
    __shared__ float kaT_s[MD * NCH];     // 32 KB [d][slot]
    __shared__ float vagg_s[NCH * MD];    // 32 KB [slot][d]
    __shared__ float G_s[MD * MD];        // 64 KB [b][d]
    __shared__ float qs[8][MD];           // 4 KB per-wave scratch
    __shared__ float attn_sh[8][64];      // 2 KB
    __shared__ float rsh_sh[8][MD];       // 4 KB   (total 138 KB)

    const int tid  = threadIdx.x;
    const int wave = tid >> 6, lane = tid & 63;
    const int row0 = blockIdx.x * 64;
    const int t = (row0 & (SEQ - 1)) >> 6;      // uniform for the whole block
    const float beta = expf(logbeta[0]);

    {
        const float4* s0 = (const float4*)kaT;
        const float4* s1 = (const float4*)vagg;
        const float4* s2 = (const float4*)G;
        float4* d0 = (float4*)kaT_s;
        float4* d1 = (float4*)vagg_s;
        float4* d2 = (float4*)G_s;
        #pragma unroll
        for (int i = 0; i < 4; ++i) {
            d0[tid + i * 512] = s0[tid + i * 512];
            d1[tid + i * 512] = s1[tid + i * 512];
        }
        #pragma unroll
        for (int i = 0; i < 8; ++i)
            d2[tid + i * 512] = s2[tid + i * 512];
    }
    __syncthreads();

    for (int rr = 0; rr < 8; ++rr) {
        const int row = row0 + wave * 8 + rr;
        float q0 = q[(size_t)row * MD + lane];
        float q1 = q[(size_t)row * MD + 64 + lane];
        qs[wave][lane]      = q0;
        qs[wave][lane + 64] = q1;   // wave-local: lgkmcnt ordering, no barrier

        float sc = -INFINITY;
        if (lane < t) {
            sc = 0.f;
            for (int d = 0; d < 128; ++d)
                sc = fmaf(qs[wave][d], kaT_s[d * NCH + lane], sc);
            sc *= beta;
        }
        float mx = sc;
        #pragma unroll
        for (int off = 32; off > 0; off >>= 1) mx = fmaxf(mx, __shfl_xor(mx, off));
        float e = (lane < t) ? expf(sc - mx) : 0.f;
        float ssum = e;
        #pragma unroll
        for (int off = 32; off > 0; off >>= 1) ssum += __shfl_xor(ssum, off);
        float attn = (t > 0) ? (e / ssum) : 0.f;
        attn_sh[wave][lane] = attn;

        float r0 = 0.f, r1 = 0.f;
        for (int n = 0; n < t; ++n) {
            float a = attn_sh[wave][n];
            r0 = fmaf(a, vagg_s[n * MD + lane], r0);
            r1 = fmaf(a, vagg_s[n * MD + 64 + lane], r1);
        }
        rsh_sh[wave][lane]      = r0;
        rsh_sh[wave][lane + 64] = r1;

        float t0 = 0.f, t1 = 0.f;
        for (int b = 0; b < 128; ++b) {
            float rb = rsh_sh[wave][b];
            t0 = fmaf(G_s[b * MD + lane], rb, t0);
            t1 = fmaf(G_s[b * MD + 64 + lane], rb, t1);
        }
        float quad = r0 * t0 + r1 * t1;
        #pragma unroll
        for (int off = 32; off > 0; off >>= 1) quad += __shfl_xor(quad, off);
        float nrm = fmaxf(sqrtf(fmaxf(quad, 0.f)), 1e-6f);
        float scl = fminf(10.f / nrm, 1.f);
        rsh16[(size_t)row * MD + lane]      = (_Float16)(r0 * scl);
        rsh16[(size_t)row * MD + 64 + lane] = (_Float16)(r1 * scl);
    }
}

// ---------------------------------------------------------------------------
// K4: out = rsh16 @ Woh^T  (16384x128)@(2048x128)^T -> f32 (16384x2048)
//   Single-shot K=128, one barrier, swizzled via pre-swizzled global source.
//   Block (0,0) additionally computes mean_ws from wstr (exact meanws
//   arithmetic; agg_combine precedes this kernel) — saves one launch.
// grid (128, 16), 256 threads
// ---------------------------------------------------------------------------
__global__ __launch_bounds__(256) void gemm_out_mfma(
    const _Float16* __restrict__ rsh16, const _Float16* __restrict__ Woh,
    float* __restrict__ C,
    const float* __restrict__ wstr, float* __restrict__ mean_out)
{
    __shared__ _Float16 As[128 * 128];   // 32 KB, 256 B rows, swizzled slots
    __shared__ _Float16 Bs[128 * 128];   // 32 KB
    floatx4 acc[4][4];
    #pragma unroll
    for (int i = 0; i < 4; ++i)
        #pragma unroll
        for (int j = 0; j < 4; ++j) acc[i][j] = (floatx4){0.f, 0.f, 0.f, 0.f};

    const int tid  = threadIdx.x;
    const int wave = tid >> 6, lane = tid & 63;
    const int wm = wave & 1, wn = wave >> 1;
    const int row0 = blockIdx.x * 128;
    const int col0 = blockIdx.y * 128;

    const int sr = lane >> 4;            // row within 4-row segment
    const int sp = lane & 15;            // physical 16B slot
    #pragma unroll
    for (int rnd = 0; rnd < 8; ++rnd) {
        int seg = wave * 8 + rnd;        // 0..31 (4 rows each)
        int r = seg * 4 + sr;            // 0..127
        int c = sp ^ (r & 15);           // source slot (swizzle pre-applied)
        gload_lds16(rsh16 + (size_t)(row0 + r) * MD + c * 8,
                    (char*)As + seg * 1024);
        gload_lds16(Woh + (size_t)(col0 + r) * MD + c * 8,
                    (char*)Bs + seg * 1024);
    }
    // meanws fold-in: exact arithmetic of the old meanws_kernel
    if (blockIdx.x == 0 && blockIdx.y == 0 && wave == 0) {
        float mv = wstr[lane];
        #pragma unroll
        for (int off = 32; off > 0; off >>= 1) mv += __shfl_xor(mv, off);
        if (lane == 0) mean_out[0] = mv * (1.f / 64.f);
    }
    __syncthreads();

    #pragma unroll
    for (int kf = 0; kf < 4; ++kf) {
        half8 af[4], bf[4];
        #pragma unroll
        for (int i = 0; i < 4; ++i) {
            int r = wm * 64 + i * 16 + (lane & 15);
            int g = kf * 4 + (lane >> 4);
            af[i] = *(const half8*)((const char*)As + r * 256 + ((g ^ (r & 15)) * 16));
        }
        #pragma unroll
        for (int j = 0; j < 4; ++j) {
            int r = wn * 64 + j * 16 + (lane & 15);
            int g = kf * 4 + (lane >> 4);
            bf[j] = *(const half8*)((const char*)Bs + r * 256 + ((g ^ (r & 15)) * 16));
        }
        #pragma unroll
        for (int i = 0; i < 4; ++i)
            #pragma unroll
            for (int j = 0; j < 4; ++j)
                acc[i][j] = __builtin_amdgcn_mfma_f32_16x16x32_f16(
                    af[i], bf[j], acc[i][j], 0, 0, 0);
    }

    #pragma unroll
    for (int i = 0; i < 4; ++i) {
        int m = row0 + wm * 64 + i * 16 + (lane >> 4) * 4;
        #pragma unroll
        for (int j = 0; j < 4; ++j) {
            int c = col0 + wn * 64 + j * 16 + (lane & 15);
            #pragma unroll
            for (int r = 0; r < 4; ++r)
                C[(size_t)(m + r) * HD + c] = acc[i][j][r];
        }
    }
}

// ---------------------------------------------------------------------------
extern "C" void kernel_launch(void* const* d_in, const int* in_sizes, int n_in,
                              void* d_out, int out_size, void* d_ws, size_t ws_size,
                              hipStream_t stream)
{
    const float* x   = (const float*)d_in[0];   // (4,4096,2048)
    const float* Wq  = (const float*)d_in[1];   // (128,2048)
    const float* Wk  = (const float*)d_in[2];
    const float* Wv  = (const float*)d_in[3];
    const float* Wo  = (const float*)d_in[4];   // (2048,128)
    const float* Wgw = (const float*)d_in[5];   // (1,2048)
    const float* Wgb = (const float*)d_in[6];   // (1,)
    const float* lb  = (const float*)d_in[7];   // (1,)
    float* out = (float*)d_out;                 // 16384*2048 + 1

    // workspace layout (16B-aligned throughout)
    float* q    = (float*)d_ws;                            // 2,097,152 f32
    float* kn   = q + (size_t)NTOK * MD;                   // normalized k
    float* vn   = kn + (size_t)NTOK * MD;                  // normalized v
    float* wg   = vn + (size_t)NTOK * MD;                  // 16384
    float* kaT  = wg + NTOK;                               // 8192
    float* vagg = kaT + MD * NCH;                          // 8192
    float* wstr = vagg + NCH * MD;                         // 64
    float* G    = wstr + 64;                               // 16384
    float* kpart = G + MD * MD;                            // 32768
    float* vpart = kpart + 256 * 128;                      // 32768
    float* wpart = vpart + 256 * 128;                      // 256
    _Float16* Wcath = (_Float16*)(wpart + 256);            // 786,432 fp16
    _Float16* Woh   = Wcath + 384 * HD;                    // 262,144 fp16
    _Float16* rsh16 = Woh + HD * MD;                       // 2,097,152 fp16

    prep_kernel<<<dim3(4096 + 128), dim3(256), 0, stream>>>(
        Wq, Wk, Wv, Wo, Wcath, Woh, G);
    gemm_proj_mfma<<<dim3(NTOK / 64, 3), dim3(256), 0, stream>>>(
        x, Wcath, Wgw, Wgb, q, kn, vn, wg);
    agg_part_kernel<<<dim3(256), dim3(256), 0, stream>>>(kn, vn, wg, kpart, vpart, wpart);
    agg_combine_kernel<<<dim3(NCH), dim3(128), 0, stream>>>(kpart, vpart, wpart, kaT, vagg, wstr);
    attn_kernel<<<dim3(NTOK / 64), dim3(512), 0, stream>>>(q, kaT, vagg, G, lb, rsh16);
    gemm_out_mfma<<<dim3(NTOK / 128, HD / 128), dim3(256), 0, stream>>>(
        rsh16, Woh, out, wstr, out + (size_t)NTOK * HD);
}

// Round 10
// 385.672 us; speedup vs baseline: 1.0200x; 1.0200x over previous
//
#include <hip/hip_runtime.h>
#include <math.h>
#include <stdint.h>

// Problem constants (fixed by setup_inputs)
#define NTOK 16384      // B*S = 4*4096
#define SEQ  4096
#define HD   2048
#define MD   128
#define NCH  64         // number of chunks == N_SLOTS (ptr never wraps)
#define CHK  64         // chunk_size

typedef __attribute__((ext_vector_type(8))) _Float16 half8;  // 8 fp16 = 4 VGPRs
typedef __attribute__((ext_vector_type(4))) float floatx4;   // MFMA accumulator

__device__ __forceinline__ void gload_lds16(const void* g, void* l) {
    // async global->LDS, 16B per lane; LDS dest = wave-uniform base + lane*16
    __builtin_amdgcn_global_load_lds(
        (const __attribute__((address_space(1))) unsigned int*)(uintptr_t)g,
        (__attribute__((address_space(3))) unsigned int*)(uintptr_t)l,
        16, 0, 0);
}

// ---------------------------------------------------------------------------
// K0: fused weight prep. Blocks 0..4095: convert weights to fp16
//   (Wcath = [Wq;Wk;Wv] 384x2048, Woh 2048x128). Blocks 4096..4223:
//   G = W_out^T @ W_out (f32), arithmetic identical to standalone gmat.
// ---------------------------------------------------------------------------
__global__ __launch_bounds__(256) void prep_kernel(
    const float* __restrict__ Wq, const float* __restrict__ Wk,
    const float* __restrict__ Wv, const float* __restrict__ Wo,
    _Float16* __restrict__ Wcath, _Float16* __restrict__ Woh,
    float* __restrict__ G)
{
    if (blockIdx.x < 4096) {
        int i = blockIdx.x * 256 + threadIdx.x;   // 0 .. 1048575
        if (i < 384 * HD) {
            int r = i >> 11;
            float val;
            if (r < 128)      val = Wq[i];
            else if (r < 256) val = Wk[i - 128 * HD];
            else              val = Wv[i - 256 * HD];
            Wcath[i] = (_Float16)val;
        } else {
            int j = i - 384 * HD;                 // 0 .. 262143
            Woh[j] = (_Float16)Wo[j];
        }
    } else {
        __shared__ float col[HD];
        int a = blockIdx.x - 4096;                // 0..127
        int tid = threadIdx.x;
        for (int j = tid; j < HD; j += 256) col[j] = Wo[(size_t)j * MD + a];
        __syncthreads();
        if (tid < 128) {
            int b = tid;
            float s = 0.f;
            for (int j = 0; j < HD; ++j) s = fmaf(col[j], Wo[(size_t)j * MD + b], s);
            G[a * MD + b] = s;
        }
    }
}

// ---------------------------------------------------------------------------
// K1 v8: proj GEMM — R7's verified 2-phase structure at DOUBLE occupancy.
//   512 threads (8 waves), same 64x128 tile, same 48 KB dbuf LDS ->
//   3 blocks/CU but 24 waves/CU (was 12). Per-wave: 16x64 sub-tile
//   (wm=wave&3 row group, wn=wave>>2 col half), acc[4], 8 MFMA/K-step.
//   Staging remapped for 512 threads with IDENTICAL byte->LDS-slot layout;
//   per-output-tile accumulation order, gate reduce tree and l2norm tree
//   unchanged -> bit-identical results. All barriers unconditional.
// grid (256, 3), 512 threads.
// ---------------------------------------------------------------------------
__global__ __launch_bounds__(512, 6) void gemm_proj_mfma(
    const float* __restrict__ x, const _Float16* __restrict__ Wcath,
    const float* __restrict__ Wgw, const float* __restrict__ gb,
    float* __restrict__ q, float* __restrict__ k, float* __restrict__ v,
    float* __restrict__ wg)
{
    __shared__ _Float16 As[2][64 * 64];    // 8 KB per buffer
    __shared__ _Float16 Bs[2][128 * 64];   // 16 KB per buffer
    floatx4 acc[4];
    #pragma unroll
    for (int j = 0; j < 4; ++j) acc[j] = (floatx4){0.f, 0.f, 0.f, 0.f};

    const int tid  = threadIdx.x;          // 0..511
    const int wave = tid >> 6, lane = tid & 63;
    const int wm = wave & 3;               // row group (16 rows)
    const int wn = wave >> 2;              // col half (64 cols)
    const int row0 = blockIdx.x * 64;
    const int col0 = blockIdx.y * 128;
    const bool do_gate = (blockIdx.y == 0);

    const int ar0 = tid >> 3;              // one row per thread, 0..63
    const int ac0 = (tid & 7) ^ (ar0 & 7); // pre-swizzled 8-f32 column group
    const float* xA0 = x + (size_t)(row0 + ar0) * HD + ac0 * 8;
    const float* wgp = Wgw + ac0 * 8;

    float gacc0 = 0.f;
    float4 a00, a01, g0, g1;

    // B staging: 16 segments x 1024 B; same (br,bc)->slot mapping as R7.
#define STAGE_B(buf_, k0_) do {                                               \
        _Pragma("unroll")                                                     \
        for (int rnd = 0; rnd < 2; ++rnd) {                                   \
            int sg = rnd * 8 + wave;                                          \
            int br = sg * 8 + (lane >> 3);                                    \
            int bc = (lane & 7) ^ (br & 7);                                   \
            gload_lds16(Wcath + (size_t)(col0 + br) * HD + (k0_) + bc * 8,    \
                        (char*)Bs[buf_] + sg * 1024);                         \
        } } while (0)

#define LOAD_A(k0_) do {                                                      \
        a00 = *(const float4*)(xA0 + (k0_));                                  \
        a01 = *(const float4*)(xA0 + (k0_) + 4);                              \
        if (do_gate) {                                                        \
            g0 = *(const float4*)(wgp + (k0_));                               \
            g1 = *(const float4*)(wgp + (k0_) + 4);                           \
        } } while (0)

#define FINISH_A(buf_) do {                                                   \
        if (do_gate) {                                                        \
            gacc0 += a00.x*g0.x + a00.y*g0.y + a00.z*g0.z + a00.w*g0.w        \
                   + a01.x*g1.x + a01.y*g1.y + a01.z*g1.z + a01.w*g1.w;       \
        }                                                                     \
        half8 h0;                                                             \
        h0[0] = (_Float16)a00.x; h0[1] = (_Float16)a00.y;                     \
        h0[2] = (_Float16)a00.z; h0[3] = (_Float16)a00.w;                     \
        h0[4] = (_Float16)a01.x; h0[5] = (_Float16)a01.y;                     \
        h0[6] = (_Float16)a01.z; h0[7] = (_Float16)a01.w;                     \
        *(half8*)((char*)As[buf_] + tid * 16) = h0;                           \
    } while (0)

#define COMPUTE(buf_) do {                                                    \
        half8 af[2], bf[4][2];                                                \
        {                                                                     \
            int r  = wm * 16 + (lane & 15);                                   \
            int rb = r * 128 + (lane >> 4) * 16;                              \
            int sw = (r & 7) << 4;                                            \
            af[0] = *(const half8*)((const char*)As[buf_] + ( rb       ^ sw));\
            af[1] = *(const half8*)((const char*)As[buf_] + ((rb + 64) ^ sw));\
        }                                                                     \
        _Pragma("unroll")                                                     \
        for (int j = 0; j < 4; ++j) {                                         \
            int r  = wn * 64 + j * 16 + (lane & 15);                          \
            int rb = r * 128 + (lane >> 4) * 16;                              \
            int sw = (r & 7) << 4;                                            \
            bf[j][0] = *(const half8*)((const char*)Bs[buf_] + ( rb       ^ sw)); \
            bf[j][1] = *(const half8*)((const char*)Bs[buf_] + ((rb + 64) ^ sw)); \
        }                                                                     \
        _Pragma("unroll")                                                     \
        for (int ks = 0; ks < 2; ++ks)                                        \
            _Pragma("unroll")                                                 \
            for (int j = 0; j < 4; ++j)                                       \
                acc[j] = __builtin_amdgcn_mfma_f32_16x16x32_f16(              \
                    af[ks], bf[j][ks], acc[j], 0, 0, 0);                      \
    } while (0)

    STAGE_B(0, 0);
    LOAD_A(0);
    FINISH_A(0);
    __syncthreads();

    int cur = 0;
    for (int t = 0; t < HD / 64; ++t) {
        if (t < HD / 64 - 1) {
            STAGE_B(cur ^ 1, (t + 1) * 64);   // async, drains at the barrier
            LOAD_A((t + 1) * 64);             // regs, consumed after MFMA
        }
        COMPUTE(cur);
        if (t < HD / 64 - 1) FINISH_A(cur ^ 1);
        __syncthreads();
        cur ^= 1;
    }

    if (do_gate) {
        // ---- gate epilogue + plain q store (same reduce tree as R7) ----
        gacc0 += __shfl_xor(gacc0, 1);
        gacc0 += __shfl_xor(gacc0, 2);
        gacc0 += __shfl_xor(gacc0, 4);
        if ((tid & 7) == 0)
            wg[row0 + ar0] = 1.f / (1.f + expf(-(gacc0 + gb[0])));
        {
            int m = row0 + wm * 16 + (lane >> 4) * 4;
            #pragma unroll
            for (int j = 0; j < 4; ++j) {
                int c = wn * 64 + j * 16 + (lane & 15);
                #pragma unroll
                for (int r = 0; r < 4; ++r)
                    q[(size_t)(m + r) * MD + c] = acc[j][r];
            }
        }
    } else {
        // ---- fused l2norm epilogue for k (y=1) / v (y=2) ----
        float* t_s = (float*)&Bs[0][0];           // [64][128] f32 overlay
        {
            int m = wm * 16 + (lane >> 4) * 4;
            #pragma unroll
            for (int j = 0; j < 4; ++j) {
                int c = wn * 64 + j * 16 + (lane & 15);
                #pragma unroll
                for (int r = 0; r < 4; ++r)
                    t_s[(m + r) * 128 + c] = acc[j][r];
            }
        }
        __syncthreads();
        float* dst = (blockIdx.y == 1) ? k : v;
        // 8 rows per wave; same per-row lane ownership + xor tree as R7.
        #pragma unroll
        for (int rr = 0; rr < 8; ++rr) {
            int row = wave * 8 + rr;
            float x0 = t_s[row * 128 + 2 * lane];
            float x1 = t_s[row * 128 + 2 * lane + 1];
            float ss = x0 * x0 + x1 * x1;
            #pragma unroll
            for (int off = 32; off > 0; off >>= 1) ss += __shfl_xor(ss, off);
            float inv = 1.f / fmaxf(sqrtf(ss), 1e-12f);
            float2 o; o.x = x0 * inv; o.y = x1 * inv;
            *(float2*)&dst[(size_t)(row0 + row) * MD + 2 * lane] = o;
        }
    }
#undef STAGE_B
#undef LOAD_A
#undef FINISH_A
#undef COMPUTE
}

// ---------------------------------------------------------------------------
// K2a: per-(chunk,batch) partial aggregation. grid 256 = chunk*4 + batch.
// ---------------------------------------------------------------------------
__global__ __launch_bounds__(256) void agg_part_kernel(
    const float* __restrict__ kn, const float* __restrict__ vn,
    const float* __restrict__ w,
    float* __restrict__ kpart, float* __restrict__ vpart,
    float* __restrict__ wpart)
{
    int t = blockIdx.x >> 2, b = blockIdx.x & 3;
    int tid = threadIdx.x;
    int d = tid & 127, h = tid >> 7;
    int base_row = b * SEQ + t * CHK;

    float ka = 0.f, va = 0.f;
    for (int c = h * 32; c < h * 32 + 32; ++c) {
        int row = base_row + c;
        float wv = w[row];
        ka = fmaf(wv, kn[(size_t)row * MD + d], ka);
        va = fmaf(wv, vn[(size_t)row * MD + d], va);
    }
    __shared__ float sk[128], sv[128];
    if (h == 1) { sk[d] = ka; sv[d] = va; }
    __syncthreads();
    if (h == 0) {
        kpart[(size_t)blockIdx.x * 128 + d] = ka + sk[d];
        vpart[(size_t)blockIdx.x * 128 + d] = va + sv[d];
    }
    if (tid < 64) {
        float wv = w[base_row + tid];
        #pragma unroll
        for (int off = 32; off > 0; off >>= 1) wv += __shfl_xor(wv, off);
        if (tid == 0) wpart[blockIdx.x] = wv;
    }
}

// ---------------------------------------------------------------------------
// K2b: combine partials per chunk, normalize, emit kaT / vagg / wstr.
// grid 64, 128 threads (2 waves)
// ---------------------------------------------------------------------------
__global__ __launch_bounds__(128) void agg_combine_kernel(
    const float* __restrict__ kpart, const float* __restrict__ vpart,
    const float* __restrict__ wpart,
    float* __restrict__ kaT, float* __restrict__ vagg, float* __restrict__ wstr)
{
    int t = blockIdx.x;
    int d = threadIdx.x;              // 0..127
    int wave = d >> 6, lane = d & 63;
    float ku = 0.f, vu = 0.f;
    #pragma unroll
    for (int b = 0; b < 4; ++b) {
        ku += kpart[(size_t)(t * 4 + b) * 128 + d];
        vu += vpart[(size_t)(t * 4 + b) * 128 + d];
    }
    float wsum = wpart[t * 4] + wpart[t * 4 + 1] + wpart[t * 4 + 2] + wpart[t * 4 + 3];
    float winv = 1.f / fmaxf(wsum, 1e-8f);
    ku *= winv; vu *= winv;

    __shared__ float red[4];
    float ks = ku * ku, vs = vu * vu;
    #pragma unroll
    for (int off = 32; off > 0; off >>= 1) {
        ks += __shfl_xor(ks, off);
        vs += __shfl_xor(vs, off);
    }
    if (lane == 0) { red[wave] = ks; red[2 + wave] = vs; }
    __syncthreads();
    float kinv = 1.f / fmaxf(sqrtf(red[0] + red[1]), 1e-12f);
    float vinv = 1.f / fmaxf(sqrtf(red[2] + red[3]), 1e-12f);
    kaT[d * NCH + t] = ku * kinv;
    vagg[t * MD + d] = vu * vinv;
    if (d == 0) wstr[t] = wsum * (1.f / 256.f);
}

// ---------------------------------------------------------------------------
// K3 v2: causal slot attention + G-norm scale; writes r (fp16) for out GEMM.
//   256 blocks (1/CU), 512 threads (8 waves), 64 rows/block; kaT+vagg+G
//   staged once into 128 KB LDS. Arithmetic order identical to v1.
// ---------------------------------------------------------------------------
__global__ __launch_bounds__(512, 1) void attn_kernel(
    const float* __restrict__ q, const float* __restrict__ kaT,
    const float* __restrict__ vagg, const float* __restrict__ G,
    const float* __restrict__ logbeta, _Float16* __restrict__ rsh16)
{
    __shared__ float kaT_s[MD * NCH];     // 32 KB [d][slot]
    __shared__ float vagg_s[NCH * MD];    // 32 KB [slot][d]
    __shared__ float G_s[MD * MD];        // 64 KB [b][d]
    __shared__ float qs[8][MD];           // 4 KB per-wave scratch
    __shared__ float attn_sh[8][64];      // 2 KB
    __shared__ float rsh_sh[8][MD];       // 4 KB   (total 138 KB)

    const int tid  = threadIdx.x;
    const int wave = tid >> 6, lane = tid & 63;
    const int row0 = blockIdx.x * 64;
    const int t = (row0 & (SEQ - 1)) >> 6;      // uniform for the whole block
    const float beta = expf(logbeta[0]);

    {
        const float4* s0 = (const float4*)kaT;
        const float4* s1 = (const float4*)vagg;
        const float4* s2 = (const float4*)G;
        float4* d0 = (float4*)kaT_s;
        float4* d1 = (float4*)vagg_s;
        float4* d2 = (float4*)G_s;
        #pragma unroll
        for (int i = 0; i < 4; ++i) {
            d0[tid + i * 512] = s0[tid + i * 512];
            d1[tid + i * 512] = s1[tid + i * 512];
        }
        #pragma unroll
        for (int i = 0; i < 8; ++i)
            d2[tid + i * 512] = s2[tid + i * 512];
    }
    __syncthreads();

    for (int rr = 0; rr < 8; ++rr) {
        const int row = row0 + wave * 8 + rr;
        float q0 = q[(size_t)row * MD + lane];
        float q1 = q[(size_t)row * MD + 64 + lane];
        qs[wave][lane]      = q0;
        qs[wave][lane + 64] = q1;   // wave-local: lgkmcnt ordering, no barrier

        float sc = -INFINITY;
        if (lane < t) {
            sc = 0.f;
            for (int d = 0; d < 128; ++d)
                sc = fmaf(qs[wave][d], kaT_s[d * NCH + lane], sc);
            sc *= beta;
        }
        float mx = sc;
        #pragma unroll
        for (int off = 32; off > 0; off >>= 1) mx = fmaxf(mx, __shfl_xor(mx, off));
        float e = (lane < t) ? expf(sc - mx) : 0.f;
        float ssum = e;
        #pragma unroll
        for (int off = 32; off > 0; off >>= 1) ssum += __shfl_xor(ssum, off);
        float attn = (t > 0) ? (e / ssum) : 0.f;
        attn_sh[wave][lane] = attn;

        float r0 = 0.f, r1 = 0.f;
        for (int n = 0; n < t; ++n) {
            float a = attn_sh[wave][n];
            r0 = fmaf(a, vagg_s[n * MD + lane], r0);
            r1 = fmaf(a, vagg_s[n * MD + 64 + lane], r1);
        }
        rsh_sh[wave][lane]      = r0;
        rsh_sh[wave][lane + 64] = r1;

        float t0 = 0.f, t1 = 0.f;
        for (int b = 0; b < 128; ++b) {
            float rb = rsh_sh[wave][b];
            t0 = fmaf(G_s[b * MD + lane], rb, t0);
            t1 = fmaf(G_s[b * MD + 64 + lane], rb, t1);
        }
        float quad = r0 * t0 + r1 * t1;
        #pragma unroll
        for (int off = 32; off > 0; off >>= 1) quad += __shfl_xor(quad, off);
        float nrm = fmaxf(sqrtf(fmaxf(quad, 0.f)), 1e-6f);
        float scl = fminf(10.f / nrm, 1.f);
        rsh16[(size_t)row * MD + lane]      = (_Float16)(r0 * scl);
        rsh16[(size_t)row * MD + 64 + lane] = (_Float16)(r1 * scl);
    }
}

// ---------------------------------------------------------------------------
// K4: out = rsh16 @ Woh^T  (16384x128)@(2048x128)^T -> f32 (16384x2048)
//   Single-shot K=128, one barrier, swizzled via pre-swizzled global source.
//   Block (0,0) additionally computes mean_ws (exact meanws arithmetic).
// grid (128, 16), 256 threads
// ---------------------------------------------------------------------------
__global__ __launch_bounds__(256) void gemm_out_mfma(
    const _Float16* __restrict__ rsh16, const _Float16* __restrict__ Woh,
    float* __restrict__ C,
    const float* __restrict__ wstr, float* __restrict__ mean_out)
{
    __shared__ _Float16 As[128 * 128];   // 32 KB, 256 B rows, swizzled slots
    __shared__ _Float16 Bs[128 * 128];   // 32 KB
    floatx4 acc[4][4];
    #pragma unroll
    for (int i = 0; i < 4; ++i)
        #pragma unroll
        for (int j = 0; j < 4; ++j) acc[i][j] = (floatx4){0.f, 0.f, 0.f, 0.f};

    const int tid  = threadIdx.x;
    const int wave = tid >> 6, lane = tid & 63;
    const int wm = wave & 1, wn = wave >> 1;
    const int row0 = blockIdx.x * 128;
    const int col0 = blockIdx.y * 128;

    const int sr = lane >> 4;            // row within 4-row segment
    const int sp = lane & 15;            // physical 16B slot
    #pragma unroll
    for (int rnd = 0; rnd < 8; ++rnd) {
        int seg = wave * 8 + rnd;        // 0..31 (4 rows each)
        int r = seg * 4 + sr;            // 0..127
        int c = sp ^ (r & 15);           // source slot (swizzle pre-applied)
        gload_lds16(rsh16 + (size_t)(row0 + r) * MD + c * 8,
                    (char*)As + seg * 1024);
        gload_lds16(Woh + (size_t)(col0 + r) * MD + c * 8,
                    (char*)Bs + seg * 1024);
    }
    // meanws fold-in: exact arithmetic of the old meanws_kernel
    if (blockIdx.x == 0 && blockIdx.y == 0 && wave == 0) {
        float mv = wstr[lane];
        #pragma unroll
        for (int off = 32; off > 0; off >>= 1) mv += __shfl_xor(mv, off);
        if (lane == 0) mean_out[0] = mv * (1.f / 64.f);
    }
    __syncthreads();

    #pragma unroll
    for (int kf = 0; kf < 4; ++kf) {
        half8 af[4], bf[4];
        #pragma unroll
        for (int i = 0; i < 4; ++i) {
            int r = wm * 64 + i * 16 + (lane & 15);
            int g = kf * 4 + (lane >> 4);
            af[i] = *(const half8*)((const char*)As + r * 256 + ((g ^ (r & 15)) * 16));
        }
        #pragma unroll
        for (int j = 0; j < 4; ++j) {
            int r = wn * 64 + j * 16 + (lane & 15);
            int g = kf * 4 + (lane >> 4);
            bf[j] = *(const half8*)((const char*)Bs + r * 256 + ((g ^ (r & 15)) * 16));
        }
        #pragma unroll
        for (int i = 0; i < 4; ++i)
            #pragma unroll
            for (int j = 0; j < 4; ++j)
                acc[i][j] = __builtin_amdgcn_mfma_f32_16x16x32_f16(
                    af[i], bf[j], acc[i][j], 0, 0, 0);
    }

    #pragma unroll
    for (int i = 0; i < 4; ++i) {
        int m = row0 + wm * 64 + i * 16 + (lane >> 4) * 4;
        #pragma unroll
        for (int j = 0; j < 4; ++j) {
            int c = col0 + wn * 64 + j * 16 + (lane & 15);
            #pragma unroll
            for (int r = 0; r < 4; ++r)
                C[(size_t)(m + r) * HD + c] = acc[i][j][r];
        }
    }
}

// ---------------------------------------------------------------------------
extern "C" void kernel_launch(void* const* d_in, const int* in_sizes, int n_in,
                              void* d_out, int out_size, void* d_ws, size_t ws_size,
                              hipStream_t stream)
{
    const float* x   = (const float*)d_in[0];   // (4,4096,2048)
    const float* Wq  = (const float*)d_in[1];   // (128,2048)
    const float* Wk  = (const float*)d_in[2];
    const float* Wv  = (const float*)d_in[3];
    const float* Wo  = (const float*)d_in[4];   // (2048,128)
    const float* Wgw = (const float*)d_in[5];   // (1,2048)
    const float* Wgb = (const float*)d_in[6];   // (1,)
    const float* lb  = (const float*)d_in[7];   // (1,)
    float* out = (float*)d_out;                 // 16384*2048 + 1

    // workspace layout (16B-aligned throughout)
    float* q    = (float*)d_ws;                            // 2,097,152 f32
    float* kn   = q + (size_t)NTOK * MD;                   // normalized k
    float* vn   = kn + (size_t)NTOK * MD;                  // normalized v
    float* wg   = vn + (size_t)NTOK * MD;                  // 16384
    float* kaT  = wg + NTOK;                               // 8192
    float* vagg = kaT + MD * NCH;                          // 8192
    float* wstr = vagg + NCH * MD;                         // 64
    float* G    = wstr + 64;                               // 16384
    float* kpart = G + MD * MD;                            // 32768
    float* vpart = kpart + 256 * 128;                      // 32768
    float* wpart = vpart + 256 * 128;                      // 256
    _Float16* Wcath = (_Float16*)(wpart + 256);            // 786,432 fp16
    _Float16* Woh   = Wcath + 384 * HD;                    // 262,144 fp16
    _Float16* rsh16 = Woh + HD * MD;                       // 2,097,152 fp16

    prep_kernel<<<dim3(4096 + 128), dim3(256), 0, stream>>>(
        Wq, Wk, Wv, Wo, Wcath, Woh, G);
    gemm_proj_mfma<<<dim3(NTOK / 64, 3), dim3(512), 0, stream>>>(
        x, Wcath, Wgw, Wgb, q, kn, vn, wg);
    agg_part_kernel<<<dim3(256), dim3(256), 0, stream>>>(kn, vn, wg, kpart, vpart, wpart);
    agg_combine_kernel<<<dim3(NCH), dim3(128), 0, stream>>>(kpart, vpart, wpart, kaT, vagg, wstr);
    attn_kernel<<<dim3(NTOK / 64), dim3(512), 0, stream>>>(q, kaT, vagg, G, lb, rsh16);
    gemm_out_mfma<<<dim3(NTOK / 128, HD / 128), dim3(256), 0, stream>>>(
        rsh16, Woh, out, wstr, out + (size_t)NTOK * HD);
}